// Round 1
// baseline (1531.231 us; speedup 1.0000x reference)
//
#include <hip/hip_runtime.h>
#include <math.h>

// Fused attention baseline, pure fp32 vector ALU.
// B=4, S=2048, D=1024. Workspace layout (fp32):
//   Q: [8192,1024]  @ 0        (32 MB)
//   K: [8192,1024]  @ 32 MB
//   V: [8192,1024]  @ 64 MB
//   S: [4,2048,2048]@ 96 MB    (64 MB)  -> total 160 MB of ws
#define BM 128
#define BN 128
#define BK 16
#define TM 8
#define TN 8

// C[M,N] = A[M,K] @ B[K,N], all row-major. Batched via blockIdx.z + strides.
__global__ __launch_bounds__(256) void sgemm_nn(
    const float* __restrict__ A, const float* __restrict__ B, float* __restrict__ C,
    int M, int N, int K,
    long long strideA, long long strideB, long long strideC)
{
    A += (long long)blockIdx.z * strideA;
    B += (long long)blockIdx.z * strideB;
    C += (long long)blockIdx.z * strideC;

    __shared__ float As[BK][BM];   // A tile, transposed: As[k][m]
    __shared__ float Bs[BK][BN];   // B tile: Bs[k][n]

    const int tid = threadIdx.x;
    const int block_row = blockIdx.y * BM;
    const int block_col = blockIdx.x * BN;
    const int tcol = (tid & 15) * TN;
    const int trow = (tid >> 4) * TM;

    float acc[TM][TN];
#pragma unroll
    for (int i = 0; i < TM; i++)
#pragma unroll
        for (int j = 0; j < TN; j++) acc[i][j] = 0.f;

    for (int k0 = 0; k0 < K; k0 += BK) {
        // A tile: 128 rows x 16 cols = 512 float4, 2 per thread
#pragma unroll
        for (int l = 0; l < 2; l++) {
            int f = tid + l * 256;
            int ar = f >> 2, ac = (f & 3) * 4;
            float4 av = *(const float4*)(A + (long long)(block_row + ar) * K + k0 + ac);
            As[ac + 0][ar] = av.x;
            As[ac + 1][ar] = av.y;
            As[ac + 2][ar] = av.z;
            As[ac + 3][ar] = av.w;
            // B tile: 16 rows x 128 cols = 512 float4
            int br = f >> 5, bc = (f & 31) * 4;
            float4 bv = *(const float4*)(B + (long long)(k0 + br) * N + block_col + bc);
            *(float4*)&Bs[br][bc] = bv;
        }
        __syncthreads();
#pragma unroll
        for (int kk = 0; kk < BK; kk++) {
            float a[TM], b[TN];
            *(float4*)&a[0] = *(const float4*)&As[kk][trow];
            *(float4*)&a[4] = *(const float4*)&As[kk][trow + 4];
            *(float4*)&b[0] = *(const float4*)&Bs[kk][tcol];
            *(float4*)&b[4] = *(const float4*)&Bs[kk][tcol + 4];
#pragma unroll
            for (int i = 0; i < TM; i++)
#pragma unroll
                for (int j = 0; j < TN; j++) acc[i][j] += a[i] * b[j];
        }
        __syncthreads();
    }
#pragma unroll
    for (int i = 0; i < TM; i++) {
        float* crow = C + (long long)(block_row + trow + i) * N + block_col + tcol;
#pragma unroll
        for (int j = 0; j < TN; j += 4) {
            *(float4*)(crow + j) = make_float4(acc[i][j], acc[i][j+1], acc[i][j+2], acc[i][j+3]);
        }
    }
}

// C[M,N] = A[M,K] @ B[N,K]^T  (i.e. C[i,j] = sum_d A[i,d]*B[j,d]), row-major.
__global__ __launch_bounds__(256) void sgemm_nt(
    const float* __restrict__ A, const float* __restrict__ B, float* __restrict__ C,
    int M, int N, int K,
    long long strideA, long long strideB, long long strideC)
{
    A += (long long)blockIdx.z * strideA;
    B += (long long)blockIdx.z * strideB;
    C += (long long)blockIdx.z * strideC;

    __shared__ float As[BK][BM];
    __shared__ float Bs[BK][BN];

    const int tid = threadIdx.x;
    const int block_row = blockIdx.y * BM;
    const int block_col = blockIdx.x * BN;
    const int tcol = (tid & 15) * TN;
    const int trow = (tid >> 4) * TM;

    float acc[TM][TN];
#pragma unroll
    for (int i = 0; i < TM; i++)
#pragma unroll
        for (int j = 0; j < TN; j++) acc[i][j] = 0.f;

    for (int k0 = 0; k0 < K; k0 += BK) {
#pragma unroll
        for (int l = 0; l < 2; l++) {
            int f = tid + l * 256;
            int ar = f >> 2, ac = (f & 3) * 4;
            float4 av = *(const float4*)(A + (long long)(block_row + ar) * K + k0 + ac);
            As[ac + 0][ar] = av.x;
            As[ac + 1][ar] = av.y;
            As[ac + 2][ar] = av.z;
            As[ac + 3][ar] = av.w;
            // B rows are keys: load B[block_col+jr][k0+jc..jc+3], scatter transposed
            int jr = f >> 2, jc = (f & 3) * 4;
            float4 bv = *(const float4*)(B + (long long)(block_col + jr) * K + k0 + jc);
            Bs[jc + 0][jr] = bv.x;
            Bs[jc + 1][jr] = bv.y;
            Bs[jc + 2][jr] = bv.z;
            Bs[jc + 3][jr] = bv.w;
        }
        __syncthreads();
#pragma unroll
        for (int kk = 0; kk < BK; kk++) {
            float a[TM], b[TN];
            *(float4*)&a[0] = *(const float4*)&As[kk][trow];
            *(float4*)&a[4] = *(const float4*)&As[kk][trow + 4];
            *(float4*)&b[0] = *(const float4*)&Bs[kk][tcol];
            *(float4*)&b[4] = *(const float4*)&Bs[kk][tcol + 4];
#pragma unroll
            for (int i = 0; i < TM; i++)
#pragma unroll
                for (int j = 0; j < TN; j++) acc[i][j] += a[i] * b[j];
        }
        __syncthreads();
    }
#pragma unroll
    for (int i = 0; i < TM; i++) {
        float* crow = C + (long long)(block_row + trow + i) * N + block_col + tcol;
#pragma unroll
        for (int j = 0; j < TN; j += 4) {
            *(float4*)(crow + j) = make_float4(acc[i][j], acc[i][j+1], acc[i][j+2], acc[i][j+3]);
        }
    }
}

// In-place row softmax: one 256-thread block per row of n=2048.
__global__ __launch_bounds__(256) void softmax_rows(float* __restrict__ S, int n)
{
    long long row = blockIdx.x;
    float* p = S + row * (long long)n;
    const int tid = threadIdx.x;
    const int wave = tid >> 6, lane = tid & 63;

    float v[8];
    float m = -3.4e38f;
#pragma unroll
    for (int i = 0; i < 8; i++) { v[i] = p[tid + (i << 8)]; m = fmaxf(m, v[i]); }
#pragma unroll
    for (int off = 32; off > 0; off >>= 1) m = fmaxf(m, __shfl_xor(m, off, 64));

    __shared__ float red[4];
    if (lane == 0) red[wave] = m;
    __syncthreads();
    m = fmaxf(fmaxf(red[0], red[1]), fmaxf(red[2], red[3]));

    float s = 0.f;
#pragma unroll
    for (int i = 0; i < 8; i++) { v[i] = __expf(v[i] - m); s += v[i]; }
#pragma unroll
    for (int off = 32; off > 0; off >>= 1) s += __shfl_xor(s, off, 64);
    __syncthreads();
    if (lane == 0) red[wave] = s;
    __syncthreads();
    s = red[0] + red[1] + red[2] + red[3];

    float inv = 1.0f / s;
#pragma unroll
    for (int i = 0; i < 8; i++) p[tid + (i << 8)] = v[i] * inv;
}

extern "C" void kernel_launch(void* const* d_in, const int* in_sizes, int n_in,
                              void* d_out, int out_size, void* d_ws, size_t ws_size,
                              hipStream_t stream) {
    const float* X  = (const float*)d_in[0];   // [4,2048,1024] = [8192,1024]
    const float* Wq = (const float*)d_in[1];   // [1024,1024]
    const float* Wk = (const float*)d_in[2];
    const float* Wv = (const float*)d_in[3];
    float* out = (float*)d_out;                // [4,2048,1024]

    const long long MD = 8192LL * 1024;        // tokens x D
    float* Q  = (float*)d_ws;
    float* Km = Q + MD;
    float* V  = Km + MD;
    float* Sc = V + MD;                        // [4,2048,2048]

    dim3 blk(256);

    // QKV projections: [8192,1024] @ [1024,1024]
    dim3 gproj(1024 / BN, 8192 / BM, 1);
    sgemm_nn<<<gproj, blk, 0, stream>>>(X, Wq, Q,  8192, 1024, 1024, 0, 0, 0);
    sgemm_nn<<<gproj, blk, 0, stream>>>(X, Wk, Km, 8192, 1024, 1024, 0, 0, 0);
    sgemm_nn<<<gproj, blk, 0, stream>>>(X, Wv, V,  8192, 1024, 1024, 0, 0, 0);

    // Scores: per batch, Q[b] @ K[b]^T  -> [2048,2048]
    dim3 gscore(2048 / BN, 2048 / BM, 4);
    sgemm_nt<<<gscore, blk, 0, stream>>>(Q, Km, Sc, 2048, 2048, 1024,
                                         2048LL * 1024, 2048LL * 1024, 2048LL * 2048);

    // Softmax over rows
    softmax_rows<<<dim3(4 * 2048), blk, 0, stream>>>(Sc, 2048);

    // Context: P[b] @ V[b] -> [2048,1024]
    dim3 gctx(1024 / BN, 2048 / BM, 4);
    sgemm_nn<<<gctx, blk, 0, stream>>>(Sc, V, out, 2048, 1024, 2048,
                                       2048LL * 2048, 2048LL * 1024, 2048LL * 1024);
}

// Round 2
// 448.146 us; speedup vs baseline: 3.4168x; 3.4168x over previous
//
#include <hip/hip_runtime.h>
#include <math.h>

// Split-bf16 MFMA attention. B=4, S=2048, D=1024.
// Scores path uses hi/lo split bf16 (3-MFMA) for fp32-like accuracy;
// V path is plain bf16 (linear error only).

typedef __bf16 bf16;
typedef __bf16 bf16x8 __attribute__((ext_vector_type(8)));
typedef __bf16 bf16x4 __attribute__((ext_vector_type(4)));
typedef float  f32x4  __attribute__((ext_vector_type(4)));

#define AS1 __attribute__((address_space(1)))
#define AS3 __attribute__((address_space(3)))

__device__ inline void async_load16(const bf16* g, void* l) {
    __builtin_amdgcn_global_load_lds((const AS1 unsigned int*)g,
                                     (AS3 unsigned int*)l, 16, 0, 0);
}

// C[M,N] = sum_k A[m,k]*B[n,k]  (B passed as [N,K] row-major).
// SPLIT: A,B given as hi/lo pairs, compute hh + hl + lh (drop ll).
// OUT_MODE: 0 = fp32 C, 1 = bf16 hi/lo pair, 2 = bf16.
template<bool SPLIT, int OUT_MODE>
__global__ __launch_bounds__(256) void gemm_bt(
    const bf16* __restrict__ Ahi, const bf16* __restrict__ Alo,
    const bf16* __restrict__ Bhi, const bf16* __restrict__ Blo,
    float* __restrict__ Cf, bf16* __restrict__ Chi, bf16* __restrict__ Clo,
    int M, int N, int K,
    long long sA, long long sB, long long sC)
{
    Ahi += (long long)blockIdx.z * sA;
    Bhi += (long long)blockIdx.z * sB;
    if (SPLIT) { Alo += (long long)blockIdx.z * sA; Blo += (long long)blockIdx.z * sB; }

    constexpr int NBUF = SPLIT ? 4 : 2;
    __shared__ bf16 smem[NBUF][128][32];   // [0]=A_hi [1]=B_hi [2]=A_lo [3]=B_lo

    const int tid  = threadIdx.x;
    const int lane = tid & 63;
    const int wave = tid >> 6;
    const int quad = lane >> 4;
    const int l16  = lane & 15;
    const int wm   = (wave >> 1) * 64;
    const int wn   = (wave & 1) * 64;

    const long long rowA0 = (long long)blockIdx.y * 128;
    const long long colB0 = (long long)blockIdx.x * 128;

    // staging: 8 KB per tile = 8 chunks of 1 KB; wave w stages chunks 2w, 2w+1.
    // byte offset o = chunk*1024 + lane*16 -> row = o>>6, col8 = (o>>4)&3
    const int o0 = (wave * 2 + 0) * 1024 + lane * 16;
    const int o1 = (wave * 2 + 1) * 1024 + lane * 16;
    const int r0 = o0 >> 6, c0 = (o0 >> 4) & 3;
    const int r1 = o1 >> 6, c1 = (o1 >> 4) & 3;

    f32x4 acc[4][4];
#pragma unroll
    for (int i = 0; i < 4; i++)
#pragma unroll
        for (int j = 0; j < 4; j++) acc[i][j] = (f32x4){0.f, 0.f, 0.f, 0.f};

    for (int k0 = 0; k0 < K; k0 += 32) {
        async_load16(Ahi + (rowA0 + r0) * K + k0 + c0 * 8, (char*)smem[0] + o0);
        async_load16(Ahi + (rowA0 + r1) * K + k0 + c1 * 8, (char*)smem[0] + o1);
        async_load16(Bhi + (colB0 + r0) * K + k0 + c0 * 8, (char*)smem[1] + o0);
        async_load16(Bhi + (colB0 + r1) * K + k0 + c1 * 8, (char*)smem[1] + o1);
        if (SPLIT) {
            async_load16(Alo + (rowA0 + r0) * K + k0 + c0 * 8, (char*)smem[2] + o0);
            async_load16(Alo + (rowA0 + r1) * K + k0 + c1 * 8, (char*)smem[2] + o1);
            async_load16(Blo + (colB0 + r0) * K + k0 + c0 * 8, (char*)smem[3] + o0);
            async_load16(Blo + (colB0 + r1) * K + k0 + c1 * 8, (char*)smem[3] + o1);
        }
        __syncthreads();

        bf16x8 a_hi[4], b_hi[4], a_lo[4], b_lo[4];
#pragma unroll
        for (int i = 0; i < 4; i++) {
            a_hi[i] = *(const bf16x8*)&smem[0][wm + i * 16 + l16][quad * 8];
            b_hi[i] = *(const bf16x8*)&smem[1][wn + i * 16 + l16][quad * 8];
            if (SPLIT) {
                a_lo[i] = *(const bf16x8*)&smem[SPLIT ? 2 : 0][wm + i * 16 + l16][quad * 8];
                b_lo[i] = *(const bf16x8*)&smem[SPLIT ? 3 : 0][wn + i * 16 + l16][quad * 8];
            }
        }
#pragma unroll
        for (int i = 0; i < 4; i++)
#pragma unroll
            for (int j = 0; j < 4; j++) {
                acc[i][j] = __builtin_amdgcn_mfma_f32_16x16x32_bf16(a_hi[i], b_hi[j], acc[i][j], 0, 0, 0);
                if (SPLIT) {
                    acc[i][j] = __builtin_amdgcn_mfma_f32_16x16x32_bf16(a_hi[i], b_lo[j], acc[i][j], 0, 0, 0);
                    acc[i][j] = __builtin_amdgcn_mfma_f32_16x16x32_bf16(a_lo[i], b_hi[j], acc[i][j], 0, 0, 0);
                }
            }
        __syncthreads();
    }

    const long long cOff = (long long)blockIdx.z * sC;
#pragma unroll
    for (int i = 0; i < 4; i++) {
        const long long rbase = rowA0 + wm + i * 16 + quad * 4;
#pragma unroll
        for (int j = 0; j < 4; j++) {
            const long long col = colB0 + wn + j * 16 + l16;
#pragma unroll
            for (int e = 0; e < 4; e++) {
                const long long idx = cOff + (rbase + e) * N + col;
                const float v = acc[i][j][e];
                if (OUT_MODE == 0) {
                    Cf[idx] = v;
                } else if (OUT_MODE == 1) {
                    bf16 h = (bf16)v;
                    Chi[idx] = h;
                    Clo[idx] = (bf16)(v - (float)h);
                } else {
                    Chi[idx] = (bf16)v;
                }
            }
        }
    }
}

// fp32 -> (hi, lo) bf16 elementwise, float4 per thread.
__global__ __launch_bounds__(256) void split_x(const float4* __restrict__ X,
                                               bf16* __restrict__ hi, bf16* __restrict__ lo,
                                               long long n4)
{
    long long i = (long long)blockIdx.x * 256 + threadIdx.x;
    if (i >= n4) return;
    float4 v = X[i];
    bf16 h0 = (bf16)v.x, h1 = (bf16)v.y, h2 = (bf16)v.z, h3 = (bf16)v.w;
    bf16x4 hv = {h0, h1, h2, h3};
    bf16x4 lv = {(bf16)(v.x - (float)h0), (bf16)(v.y - (float)h1),
                 (bf16)(v.z - (float)h2), (bf16)(v.w - (float)h3)};
    *(bf16x4*)(hi + 4 * i) = hv;
    *(bf16x4*)(lo + 4 * i) = lv;
}

// W fp32 [R][C] -> transposed split bf16 [C][R] (hi, lo).
__global__ __launch_bounds__(256) void wsplit_t(const float* __restrict__ W,
                                                bf16* __restrict__ Thi, bf16* __restrict__ Tlo,
                                                int R, int C)
{
    __shared__ float t[32][33];
    const int bx = blockIdx.x * 32, by = blockIdx.y * 32;
    const int tx = threadIdx.x & 31, ty = threadIdx.x >> 5;
#pragma unroll
    for (int i = 0; i < 32; i += 8)
        t[ty + i][tx] = W[(long long)(by + ty + i) * C + bx + tx];
    __syncthreads();
#pragma unroll
    for (int i = 0; i < 32; i += 8) {
        float v = t[tx][ty + i];                       // = W[by+tx][bx+ty+i]
        long long o = (long long)(bx + ty + i) * R + by + tx;
        bf16 h = (bf16)v;
        Thi[o] = h;
        Tlo[o] = (bf16)(v - (float)h);
    }
}

// bf16 [R][C] -> bf16 [C][R], batched via blockIdx.z.
__global__ __launch_bounds__(256) void transpose_bf16(const bf16* __restrict__ in,
                                                      bf16* __restrict__ out,
                                                      int R, int C, long long sIn, long long sOut)
{
    in  += (long long)blockIdx.z * sIn;
    out += (long long)blockIdx.z * sOut;
    __shared__ bf16 t[32][33];
    const int bx = blockIdx.x * 32, by = blockIdx.y * 32;
    const int tx = threadIdx.x & 31, ty = threadIdx.x >> 5;
#pragma unroll
    for (int i = 0; i < 32; i += 8)
        t[ty + i][tx] = in[(long long)(by + ty + i) * C + bx + tx];
    __syncthreads();
#pragma unroll
    for (int i = 0; i < 32; i += 8)
        out[(long long)(bx + ty + i) * R + by + tx] = t[tx][ty + i];
}

// Row softmax fp32 -> bf16. One 256-thread block per row of n=2048.
__global__ __launch_bounds__(256) void softmax_bf16(const float* __restrict__ S,
                                                    bf16* __restrict__ P, int n)
{
    const long long row = blockIdx.x;
    const float* p = S + row * (long long)n;
    bf16* q = P + row * (long long)n;
    const int tid = threadIdx.x;
    const int wv = tid >> 6, lane = tid & 63;

    float v[8];
    float m = -3.4e38f;
#pragma unroll
    for (int i = 0; i < 8; i++) { v[i] = p[tid + (i << 8)]; m = fmaxf(m, v[i]); }
#pragma unroll
    for (int off = 32; off > 0; off >>= 1) m = fmaxf(m, __shfl_xor(m, off, 64));

    __shared__ float red[4];
    if (lane == 0) red[wv] = m;
    __syncthreads();
    m = fmaxf(fmaxf(red[0], red[1]), fmaxf(red[2], red[3]));

    float s = 0.f;
#pragma unroll
    for (int i = 0; i < 8; i++) { v[i] = __expf(v[i] - m); s += v[i]; }
#pragma unroll
    for (int off = 32; off > 0; off >>= 1) s += __shfl_xor(s, off, 64);
    __syncthreads();
    if (lane == 0) red[wv] = s;
    __syncthreads();
    s = red[0] + red[1] + red[2] + red[3];

    const float inv = 1.0f / s;
#pragma unroll
    for (int i = 0; i < 8; i++) q[tid + (i << 8)] = (bf16)(v[i] * inv);
}

extern "C" void kernel_launch(void* const* d_in, const int* in_sizes, int n_in,
                              void* d_out, int out_size, void* d_ws, size_t ws_size,
                              hipStream_t stream) {
    const float* X  = (const float*)d_in[0];   // [8192,1024]
    const float* Wq = (const float*)d_in[1];   // [1024,1024]
    const float* Wk = (const float*)d_in[2];
    const float* Wv = (const float*)d_in[3];
    float* out = (float*)d_out;                // [8192,1024]

    const long long MD = 8192LL * 1024;        // 8,388,608
    const long long DD = 1024LL * 1024;
    const long long SS = 2048LL * 2048;

    char* w = (char*)d_ws;
    const long long MB = 1024LL * 1024;
    bf16* Xhi   = (bf16*)(w + 0 * MB);
    bf16* Xlo   = (bf16*)(w + 16 * MB);
    bf16* Wqt_h = (bf16*)(w + 32 * MB);
    bf16* Wqt_l = (bf16*)(w + 34 * MB);
    bf16* Wkt_h = (bf16*)(w + 36 * MB);
    bf16* Wkt_l = (bf16*)(w + 38 * MB);
    bf16* Wvt_h = (bf16*)(w + 40 * MB);
    bf16* Wvt_l = (bf16*)(w + 42 * MB);
    bf16* Qhi   = (bf16*)(w + 44 * MB);
    bf16* Qlo   = (bf16*)(w + 60 * MB);
    bf16* Khi   = (bf16*)(w + 76 * MB);
    bf16* Klo   = (bf16*)(w + 92 * MB);
    bf16* Vb    = (bf16*)(w + 108 * MB);
    bf16* Vt    = (bf16*)(w + 124 * MB);
    float* Sc   = (float*)(w + 140 * MB);      // 64 MB
    bf16* P     = (bf16*)(w + 204 * MB);       // 32 MB -> ends 236 MB

    dim3 blk(256);

    // 1. split X
    split_x<<<dim3((unsigned)(MD / 4 / 256)), blk, 0, stream>>>((const float4*)X, Xhi, Xlo, MD / 4);

    // 2. transpose+split weights
    dim3 gt(32, 32, 1);
    wsplit_t<<<gt, blk, 0, stream>>>(Wq, Wqt_h, Wqt_l, 1024, 1024);
    wsplit_t<<<gt, blk, 0, stream>>>(Wk, Wkt_h, Wkt_l, 1024, 1024);
    wsplit_t<<<gt, blk, 0, stream>>>(Wv, Wvt_h, Wvt_l, 1024, 1024);

    // 3. Q, K projections (split, bf16 hi/lo out); V projection (plain, bf16 out)
    dim3 gproj(1024 / 128, 8192 / 128, 1);
    gemm_bt<true, 1><<<gproj, blk, 0, stream>>>(Xhi, Xlo, Wqt_h, Wqt_l,
                                                nullptr, Qhi, Qlo, 8192, 1024, 1024, 0, 0, 0);
    gemm_bt<true, 1><<<gproj, blk, 0, stream>>>(Xhi, Xlo, Wkt_h, Wkt_l,
                                                nullptr, Khi, Klo, 8192, 1024, 1024, 0, 0, 0);
    gemm_bt<false, 2><<<gproj, blk, 0, stream>>>(Xhi, nullptr, Wvt_h, nullptr,
                                                 nullptr, Vb, nullptr, 8192, 1024, 1024, 0, 0, 0);

    // 4. V -> V^T per batch: [2048,1024] -> [1024,2048]
    transpose_bf16<<<dim3(1024 / 32, 2048 / 32, 4), blk, 0, stream>>>(
        Vb, Vt, 2048, 1024, 2048LL * 1024, 1024LL * 2048);

    // 5. scores = Q K^T (split), fp32 out
    dim3 gsc(2048 / 128, 2048 / 128, 4);
    gemm_bt<true, 0><<<gsc, blk, 0, stream>>>(Qhi, Qlo, Khi, Klo,
                                              Sc, nullptr, nullptr, 2048, 2048, 1024,
                                              2048LL * 1024, 2048LL * 1024, SS);

    // 6. softmax rows -> bf16 P
    softmax_bf16<<<dim3(4 * 2048), blk, 0, stream>>>(Sc, P, 2048);

    // 7. out = P V  (A=P [2048x2048], B=Vt [1024 rows x 2048])
    dim3 gpv(1024 / 128, 2048 / 128, 4);
    gemm_bt<false, 0><<<gpv, blk, 0, stream>>>(P, nullptr, Vt, nullptr,
                                               out, nullptr, nullptr, 2048, 1024, 2048,
                                               SS, 1024LL * 2048, 2048LL * 1024);
}

// Round 3
// 396.485 us; speedup vs baseline: 3.8620x; 1.1303x over previous
//
#include <hip/hip_runtime.h>
#include <math.h>

// Round 3: split-bf16 projections (3-MFMA, fp32-like accuracy), fp16 single-MFMA
// scores + PV. B=4, S=2048, D=1024.
//
// Numerics: Q,K must be accurate to ~1e-4 rel (softmax amplifies score error
// ~50x), so X->QK projection uses bf16 hi/lo split (bf16 keeps fp32 exponent
// range; fp16 W_lo ~7.6e-6 would hit the f16 subnormal/flush hazard).
// Q,K stored fp16 (2^-11 rounding -> score err ~6e-3 rms -> out err ~0.03,
// threshold 0.106). Scores/PV are then plain f16 MFMA at 1x flops.

typedef __bf16 bf16;
typedef _Float16 f16;
typedef __bf16 bf16x8 __attribute__((ext_vector_type(8)));
typedef __bf16 bf16x4 __attribute__((ext_vector_type(4)));
typedef _Float16 f16x8 __attribute__((ext_vector_type(8)));
typedef float  f32x4  __attribute__((ext_vector_type(4)));

template<typename E> struct vec8_of;
template<> struct vec8_of<bf16> { using type = bf16x8; };
template<> struct vec8_of<f16>  { using type = f16x8; };

__device__ inline f32x4 mfma16(bf16x8 a, bf16x8 b, f32x4 c) {
    return __builtin_amdgcn_mfma_f32_16x16x32_bf16(a, b, c, 0, 0, 0);
}
__device__ inline f32x4 mfma16(f16x8 a, f16x8 b, f32x4 c) {
    return __builtin_amdgcn_mfma_f32_16x16x32_f16(a, b, c, 0, 0, 0);
}

#define AS1 __attribute__((address_space(1)))
#define AS3 __attribute__((address_space(3)))

template<typename E>
__device__ inline void async_load16(const E* g, void* l) {
    __builtin_amdgcn_global_load_lds((const AS1 unsigned int*)g,
                                     (AS3 unsigned int*)l, 16, 0, 0);
}

// C[M,N] = sum_k A[m,k]*B[n,k]  (B passed as [N,K]-layout with leading dim ldb).
// SPLIT: hi/lo pairs, compute hh + hl + lh (drop ll).
// OUT_MODE: 0 = fp32 C, 1 = fp16 C.
template<typename E, bool SPLIT, int OUT_MODE>
__global__ __launch_bounds__(256) void gemm_bt(
    const E* __restrict__ Ahi, const E* __restrict__ Alo,
    const E* __restrict__ Bhi, const E* __restrict__ Blo,
    float* __restrict__ Cf, f16* __restrict__ Ch,
    int K, int lda, int ldb, int ldc,
    long long sA, long long sB, long long sC)
{
    using vec8 = typename vec8_of<E>::type;

    Ahi += (long long)blockIdx.z * sA;
    Bhi += (long long)blockIdx.z * sB;
    if (SPLIT) { Alo += (long long)blockIdx.z * sA; Blo += (long long)blockIdx.z * sB; }

    constexpr int NBUF = SPLIT ? 4 : 2;
    __shared__ E smem[NBUF][128][32];   // [0]=A_hi [1]=B_hi [2]=A_lo [3]=B_lo

    const int tid  = threadIdx.x;
    const int lane = tid & 63;
    const int wave = tid >> 6;
    const int quad = lane >> 4;
    const int l16  = lane & 15;
    const int wm   = (wave >> 1) * 64;
    const int wn   = (wave & 1) * 64;

    const long long rowA0 = (long long)blockIdx.y * 128;
    const long long colB0 = (long long)blockIdx.x * 128;

    // staging: 8 KB per tile = 8 chunks of 1 KB; wave w stages chunks 2w, 2w+1.
    const int o0 = (wave * 2 + 0) * 1024 + lane * 16;
    const int o1 = (wave * 2 + 1) * 1024 + lane * 16;
    const int r0 = o0 >> 6, c0 = (o0 >> 4) & 3;
    const int r1 = o1 >> 6, c1 = (o1 >> 4) & 3;

    f32x4 acc[4][4];
#pragma unroll
    for (int i = 0; i < 4; i++)
#pragma unroll
        for (int j = 0; j < 4; j++) acc[i][j] = (f32x4){0.f, 0.f, 0.f, 0.f};

    for (int k0 = 0; k0 < K; k0 += 32) {
        async_load16(Ahi + (rowA0 + r0) * lda + k0 + c0 * 8, (char*)smem[0] + o0);
        async_load16(Ahi + (rowA0 + r1) * lda + k0 + c1 * 8, (char*)smem[0] + o1);
        async_load16(Bhi + (colB0 + r0) * ldb + k0 + c0 * 8, (char*)smem[1] + o0);
        async_load16(Bhi + (colB0 + r1) * ldb + k0 + c1 * 8, (char*)smem[1] + o1);
        if (SPLIT) {
            async_load16(Alo + (rowA0 + r0) * lda + k0 + c0 * 8, (char*)smem[2] + o0);
            async_load16(Alo + (rowA0 + r1) * lda + k0 + c1 * 8, (char*)smem[2] + o1);
            async_load16(Blo + (colB0 + r0) * ldb + k0 + c0 * 8, (char*)smem[3] + o0);
            async_load16(Blo + (colB0 + r1) * ldb + k0 + c1 * 8, (char*)smem[3] + o1);
        }
        __syncthreads();

        vec8 a_hi[4], b_hi[4], a_lo[4], b_lo[4];
#pragma unroll
        for (int i = 0; i < 4; i++) {
            a_hi[i] = *(const vec8*)&smem[0][wm + i * 16 + l16][quad * 8];
            b_hi[i] = *(const vec8*)&smem[1][wn + i * 16 + l16][quad * 8];
            if (SPLIT) {
                a_lo[i] = *(const vec8*)&smem[SPLIT ? 2 : 0][wm + i * 16 + l16][quad * 8];
                b_lo[i] = *(const vec8*)&smem[SPLIT ? 3 : 0][wn + i * 16 + l16][quad * 8];
            }
        }
#pragma unroll
        for (int i = 0; i < 4; i++)
#pragma unroll
            for (int j = 0; j < 4; j++) {
                acc[i][j] = mfma16(a_hi[i], b_hi[j], acc[i][j]);
                if (SPLIT) {
                    acc[i][j] = mfma16(a_hi[i], b_lo[j], acc[i][j]);
                    acc[i][j] = mfma16(a_lo[i], b_hi[j], acc[i][j]);
                }
            }
        __syncthreads();
    }

    const long long cOff = (long long)blockIdx.z * sC;
#pragma unroll
    for (int i = 0; i < 4; i++) {
        const long long rbase = rowA0 + wm + i * 16 + quad * 4;
#pragma unroll
        for (int j = 0; j < 4; j++) {
            const long long col = colB0 + wn + j * 16 + l16;
#pragma unroll
            for (int e = 0; e < 4; e++) {
                const long long idx = cOff + (rbase + e) * ldc + col;
                const float v = acc[i][j][e];
                if (OUT_MODE == 0) Cf[idx] = v;
                else               Ch[idx] = (f16)v;
            }
        }
    }
}

// fp32 -> (hi, lo) bf16 elementwise, float4 per thread.
__global__ __launch_bounds__(256) void split_x(const float4* __restrict__ X,
                                               bf16* __restrict__ hi, bf16* __restrict__ lo,
                                               long long n4)
{
    long long i = (long long)blockIdx.x * 256 + threadIdx.x;
    if (i >= n4) return;
    float4 v = X[i];
    bf16 h0 = (bf16)v.x, h1 = (bf16)v.y, h2 = (bf16)v.z, h3 = (bf16)v.w;
    bf16x4 hv = {h0, h1, h2, h3};
    bf16x4 lv = {(bf16)(v.x - (float)h0), (bf16)(v.y - (float)h1),
                 (bf16)(v.z - (float)h2), (bf16)(v.w - (float)h3)};
    *(bf16x4*)(hi + 4 * i) = hv;
    *(bf16x4*)(lo + 4 * i) = lv;
}

// W fp32 [R][C] -> transposed split bf16 [C][R] (hi, lo). Caller pre-offsets
// Thi/Tlo for row placement inside a larger [N][R] buffer.
__global__ __launch_bounds__(256) void wsplit_t(const float* __restrict__ W,
                                                bf16* __restrict__ Thi, bf16* __restrict__ Tlo,
                                                int R, int C)
{
    __shared__ float t[32][33];
    const int bx = blockIdx.x * 32, by = blockIdx.y * 32;
    const int tx = threadIdx.x & 31, ty = threadIdx.x >> 5;
#pragma unroll
    for (int i = 0; i < 32; i += 8)
        t[ty + i][tx] = W[(long long)(by + ty + i) * C + bx + tx];
    __syncthreads();
#pragma unroll
    for (int i = 0; i < 32; i += 8) {
        float v = t[tx][ty + i];                       // = W[by+tx][bx+ty+i]
        long long o = (long long)(bx + ty + i) * R + by + tx;
        bf16 h = (bf16)v;
        Thi[o] = h;
        Tlo[o] = (bf16)(v - (float)h);
    }
}

// f16 [R][C] -> f16 [C][R], batched via blockIdx.z.
__global__ __launch_bounds__(256) void transpose_f16(const f16* __restrict__ in,
                                                     f16* __restrict__ out,
                                                     int R, int C, long long sIn, long long sOut)
{
    in  += (long long)blockIdx.z * sIn;
    out += (long long)blockIdx.z * sOut;
    __shared__ f16 t[32][33];
    const int bx = blockIdx.x * 32, by = blockIdx.y * 32;
    const int tx = threadIdx.x & 31, ty = threadIdx.x >> 5;
#pragma unroll
    for (int i = 0; i < 32; i += 8)
        t[ty + i][tx] = in[(long long)(by + ty + i) * C + bx + tx];
    __syncthreads();
#pragma unroll
    for (int i = 0; i < 32; i += 8)
        out[(long long)(bx + ty + i) * R + by + tx] = t[tx][ty + i];
}

// Row softmax fp32 -> f16. One 256-thread block per row of n=2048.
__global__ __launch_bounds__(256) void softmax_f16(const float* __restrict__ S,
                                                   f16* __restrict__ P, int n)
{
    const long long row = blockIdx.x;
    const float* p = S + row * (long long)n;
    f16* q = P + row * (long long)n;
    const int tid = threadIdx.x;
    const int wv = tid >> 6, lane = tid & 63;

    float v[8];
    float m = -3.4e38f;
#pragma unroll
    for (int i = 0; i < 8; i++) { v[i] = p[tid + (i << 8)]; m = fmaxf(m, v[i]); }
#pragma unroll
    for (int off = 32; off > 0; off >>= 1) m = fmaxf(m, __shfl_xor(m, off, 64));

    __shared__ float red[4];
    if (lane == 0) red[wv] = m;
    __syncthreads();
    m = fmaxf(fmaxf(red[0], red[1]), fmaxf(red[2], red[3]));

    float s = 0.f;
#pragma unroll
    for (int i = 0; i < 8; i++) { v[i] = __expf(v[i] - m); s += v[i]; }
#pragma unroll
    for (int off = 32; off > 0; off >>= 1) s += __shfl_xor(s, off, 64);
    __syncthreads();
    if (lane == 0) red[wv] = s;
    __syncthreads();
    s = red[0] + red[1] + red[2] + red[3];

    const float inv = 1.0f / s;
#pragma unroll
    for (int i = 0; i < 8; i++) q[tid + (i << 8)] = (f16)(v[i] * inv);
}

extern "C" void kernel_launch(void* const* d_in, const int* in_sizes, int n_in,
                              void* d_out, int out_size, void* d_ws, size_t ws_size,
                              hipStream_t stream) {
    const float* X  = (const float*)d_in[0];   // [8192,1024]
    const float* Wq = (const float*)d_in[1];   // [1024,1024]
    const float* Wk = (const float*)d_in[2];
    const float* Wv = (const float*)d_in[3];
    float* out = (float*)d_out;                // [8192,1024]

    const long long MD = 8192LL * 1024;

    char* w = (char*)d_ws;
    const long long MB = 1024LL * 1024;
    bf16* Xhi   = (bf16*)(w + 0 * MB);     // 16 MB
    bf16* Xlo   = (bf16*)(w + 16 * MB);    // 16 MB
    bf16* Wqk_h = (bf16*)(w + 32 * MB);    // [2048][1024] bf16 = 4 MB
    bf16* Wqk_l = (bf16*)(w + 36 * MB);    // 4 MB
    bf16* Wv_h  = (bf16*)(w + 40 * MB);    // 2 MB
    bf16* Wv_l  = (bf16*)(w + 42 * MB);    // 2 MB
    f16*  QKf   = (f16*) (w + 44 * MB);    // [8192][2048] f16 = 32 MB
    f16*  Vb    = (f16*) (w + 76 * MB);    // 16 MB
    f16*  Vt    = (f16*) (w + 92 * MB);    // 16 MB
    float* Sc   = (float*)(w + 108 * MB);  // 64 MB
    f16*  P     = (f16*) (w + 172 * MB);   // 32 MB -> ends 204 MB

    dim3 blk(256);

    // 1. split X into bf16 hi/lo
    split_x<<<dim3((unsigned)(MD / 4 / 256)), blk, 0, stream>>>((const float4*)X, Xhi, Xlo, MD / 4);

    // 2. transpose+split weights: Wq->rows 0..1023, Wk->rows 1024..2047 of Wqk
    dim3 gt(32, 32, 1);
    wsplit_t<<<gt, blk, 0, stream>>>(Wq, Wqk_h,                Wqk_l,                1024, 1024);
    wsplit_t<<<gt, blk, 0, stream>>>(Wk, Wqk_h + 1024LL * 1024, Wqk_l + 1024LL * 1024, 1024, 1024);
    wsplit_t<<<gt, blk, 0, stream>>>(Wv, Wv_h,                 Wv_l,                 1024, 1024);

    // 3. merged Q|K projection (split-bf16, 3-MFMA), output single fp16 [8192][2048]
    dim3 gqk(2048 / 128, 8192 / 128, 1);
    gemm_bt<bf16, true, 1><<<gqk, blk, 0, stream>>>(
        Xhi, Xlo, Wqk_h, Wqk_l, nullptr, QKf,
        1024, 1024, 1024, 2048, 0, 0, 0);

    // 4. V projection (plain bf16), output fp16
    dim3 gv(1024 / 128, 8192 / 128, 1);
    gemm_bt<bf16, false, 1><<<gv, blk, 0, stream>>>(
        Xhi, nullptr, Wv_h, nullptr, nullptr, Vb,
        1024, 1024, 1024, 1024, 0, 0, 0);

    // 5. V -> V^T per batch: [2048,1024] -> [1024,2048]
    transpose_f16<<<dim3(1024 / 32, 2048 / 32, 4), blk, 0, stream>>>(
        Vb, Vt, 2048, 1024, 2048LL * 1024, 1024LL * 2048);

    // 6. scores = Q K^T, plain f16 MFMA, fp32 out.
    //    A = QKf cols 0..1023 (Q), B = QKf cols 1024..2047 (K), both ld 2048.
    dim3 gsc(2048 / 128, 2048 / 128, 4);
    gemm_bt<f16, false, 0><<<gsc, blk, 0, stream>>>(
        QKf, nullptr, QKf + 1024, nullptr, Sc, nullptr,
        1024, 2048, 2048, 2048,
        2048LL * 2048, 2048LL * 2048, 2048LL * 2048);

    // 7. softmax rows -> f16 P
    softmax_f16<<<dim3(4 * 2048), blk, 0, stream>>>(Sc, P, 2048);

    // 8. out = P V   (A = P [2048x2048], B = Vt [1024 x 2048])
    dim3 gpv(1024 / 128, 2048 / 128, 4);
    gemm_bt<f16, false, 0><<<gpv, blk, 0, stream>>>(
        P, nullptr, Vt, nullptr, out, nullptr,
        2048, 2048, 2048, 1024,
        2048LL * 2048, 1024LL * 2048, 2048LL * 1024);
}

// Round 4
// 381.047 us; speedup vs baseline: 4.0185x; 1.0405x over previous
//
#include <hip/hip_runtime.h>
#include <math.h>

// Round 4: scores = X (Wq Wk^T) X^T restructure.
//   M^T = Wk Wq^T  (split-bf16, 2.1 GF)         -> fp32, split to bf16 hi/lo
//   T   = Xsplit . M^T_split (3-MFMA, 17.2 GF)  -> f16 [8192,1024]
//   S   = T . X^T (plain f16 MFMA, 34.4 GF)     -> fp32
// Identical error structure to R3's Qf16.Kf16^T (T,X std 1 stored f16),
// but 45 GF-exec less MFMA work. V path unchanged (plain bf16 linear error).

typedef __bf16 bf16;
typedef _Float16 f16;
typedef __bf16 bf16x8 __attribute__((ext_vector_type(8)));
typedef __bf16 bf16x4 __attribute__((ext_vector_type(4)));
typedef _Float16 f16x4 __attribute__((ext_vector_type(4)));
typedef _Float16 f16x8 __attribute__((ext_vector_type(8)));
typedef float  f32x4  __attribute__((ext_vector_type(4)));

template<typename E> struct vec8_of;
template<> struct vec8_of<bf16> { using type = bf16x8; };
template<> struct vec8_of<f16>  { using type = f16x8; };

__device__ inline f32x4 mfma16(bf16x8 a, bf16x8 b, f32x4 c) {
    return __builtin_amdgcn_mfma_f32_16x16x32_bf16(a, b, c, 0, 0, 0);
}
__device__ inline f32x4 mfma16(f16x8 a, f16x8 b, f32x4 c) {
    return __builtin_amdgcn_mfma_f32_16x16x32_f16(a, b, c, 0, 0, 0);
}

#define AS1 __attribute__((address_space(1)))
#define AS3 __attribute__((address_space(3)))

template<typename E>
__device__ inline void async_load16(const E* g, void* l) {
    __builtin_amdgcn_global_load_lds((const AS1 unsigned int*)g,
                                     (AS3 unsigned int*)l, 16, 0, 0);
}

// C[M,N] = sum_k A[m,k]*B[n,k]  (B passed as [N,K]-layout with leading dim ldb).
// SPLIT: hi/lo pairs, compute hh + hl + lh (drop ll).
// OUT_MODE: 0 = fp32 C, 1 = fp16 C.
template<typename E, bool SPLIT, int OUT_MODE>
__global__ __launch_bounds__(256) void gemm_bt(
    const E* __restrict__ Ahi, const E* __restrict__ Alo,
    const E* __restrict__ Bhi, const E* __restrict__ Blo,
    float* __restrict__ Cf, f16* __restrict__ Ch,
    int K, int lda, int ldb, int ldc,
    long long sA, long long sB, long long sC)
{
    using vec8 = typename vec8_of<E>::type;

    Ahi += (long long)blockIdx.z * sA;
    Bhi += (long long)blockIdx.z * sB;
    if (SPLIT) { Alo += (long long)blockIdx.z * sA; Blo += (long long)blockIdx.z * sB; }

    constexpr int NBUF = SPLIT ? 4 : 2;
    __shared__ E smem[NBUF][128][32];   // [0]=A_hi [1]=B_hi [2]=A_lo [3]=B_lo

    const int tid  = threadIdx.x;
    const int lane = tid & 63;
    const int wave = tid >> 6;
    const int quad = lane >> 4;
    const int l16  = lane & 15;
    const int wm   = (wave >> 1) * 64;
    const int wn   = (wave & 1) * 64;

    const long long rowA0 = (long long)blockIdx.y * 128;
    const long long colB0 = (long long)blockIdx.x * 128;

    // staging: 8 KB per tile = 8 chunks of 1 KB; wave w stages chunks 2w, 2w+1.
    const int o0 = (wave * 2 + 0) * 1024 + lane * 16;
    const int o1 = (wave * 2 + 1) * 1024 + lane * 16;
    const int r0 = o0 >> 6, c0 = (o0 >> 4) & 3;
    const int r1 = o1 >> 6, c1 = (o1 >> 4) & 3;

    f32x4 acc[4][4];
#pragma unroll
    for (int i = 0; i < 4; i++)
#pragma unroll
        for (int j = 0; j < 4; j++) acc[i][j] = (f32x4){0.f, 0.f, 0.f, 0.f};

    for (int k0 = 0; k0 < K; k0 += 32) {
        async_load16(Ahi + (rowA0 + r0) * lda + k0 + c0 * 8, (char*)smem[0] + o0);
        async_load16(Ahi + (rowA0 + r1) * lda + k0 + c1 * 8, (char*)smem[0] + o1);
        async_load16(Bhi + (colB0 + r0) * ldb + k0 + c0 * 8, (char*)smem[1] + o0);
        async_load16(Bhi + (colB0 + r1) * ldb + k0 + c1 * 8, (char*)smem[1] + o1);
        if (SPLIT) {
            async_load16(Alo + (rowA0 + r0) * lda + k0 + c0 * 8, (char*)smem[2] + o0);
            async_load16(Alo + (rowA0 + r1) * lda + k0 + c1 * 8, (char*)smem[2] + o1);
            async_load16(Blo + (colB0 + r0) * ldb + k0 + c0 * 8, (char*)smem[3] + o0);
            async_load16(Blo + (colB0 + r1) * ldb + k0 + c1 * 8, (char*)smem[3] + o1);
        }
        __syncthreads();

        vec8 a_hi[4], b_hi[4], a_lo[4], b_lo[4];
#pragma unroll
        for (int i = 0; i < 4; i++) {
            a_hi[i] = *(const vec8*)&smem[0][wm + i * 16 + l16][quad * 8];
            b_hi[i] = *(const vec8*)&smem[1][wn + i * 16 + l16][quad * 8];
            if (SPLIT) {
                a_lo[i] = *(const vec8*)&smem[SPLIT ? 2 : 0][wm + i * 16 + l16][quad * 8];
                b_lo[i] = *(const vec8*)&smem[SPLIT ? 3 : 0][wn + i * 16 + l16][quad * 8];
            }
        }
#pragma unroll
        for (int i = 0; i < 4; i++)
#pragma unroll
            for (int j = 0; j < 4; j++) {
                acc[i][j] = mfma16(a_hi[i], b_hi[j], acc[i][j]);
                if (SPLIT) {
                    acc[i][j] = mfma16(a_hi[i], b_lo[j], acc[i][j]);
                    acc[i][j] = mfma16(a_lo[i], b_hi[j], acc[i][j]);
                }
            }
        __syncthreads();
    }

    const long long cOff = (long long)blockIdx.z * sC;
#pragma unroll
    for (int i = 0; i < 4; i++) {
        const long long rbase = rowA0 + wm + i * 16 + quad * 4;
#pragma unroll
        for (int j = 0; j < 4; j++) {
            const long long col = colB0 + wn + j * 16 + l16;
#pragma unroll
            for (int e = 0; e < 4; e++) {
                const long long idx = cOff + (rbase + e) * ldc + col;
                const float v = acc[i][j][e];
                if (OUT_MODE == 0) Cf[idx] = v;
                else               Ch[idx] = (f16)v;
            }
        }
    }
}

// fp32 -> (hi, lo) bf16 + optional f16 copy, elementwise, float4 per thread.
__global__ __launch_bounds__(256) void split_x(const float4* __restrict__ X,
                                               bf16* __restrict__ hi, bf16* __restrict__ lo,
                                               f16* __restrict__ xf,
                                               long long n4)
{
    long long i = (long long)blockIdx.x * 256 + threadIdx.x;
    if (i >= n4) return;
    float4 v = X[i];
    bf16 h0 = (bf16)v.x, h1 = (bf16)v.y, h2 = (bf16)v.z, h3 = (bf16)v.w;
    bf16x4 hv = {h0, h1, h2, h3};
    bf16x4 lv = {(bf16)(v.x - (float)h0), (bf16)(v.y - (float)h1),
                 (bf16)(v.z - (float)h2), (bf16)(v.w - (float)h3)};
    *(bf16x4*)(hi + 4 * i) = hv;
    *(bf16x4*)(lo + 4 * i) = lv;
    if (xf) {
        f16x4 fv = {(f16)v.x, (f16)v.y, (f16)v.z, (f16)v.w};
        *(f16x4*)(xf + 4 * i) = fv;
    }
}

// W fp32 [R][C] -> transposed split bf16 [C][R] (hi, lo).
__global__ __launch_bounds__(256) void wsplit_t(const float* __restrict__ W,
                                                bf16* __restrict__ Thi, bf16* __restrict__ Tlo,
                                                int R, int C)
{
    __shared__ float t[32][33];
    const int bx = blockIdx.x * 32, by = blockIdx.y * 32;
    const int tx = threadIdx.x & 31, ty = threadIdx.x >> 5;
#pragma unroll
    for (int i = 0; i < 32; i += 8)
        t[ty + i][tx] = W[(long long)(by + ty + i) * C + bx + tx];
    __syncthreads();
#pragma unroll
    for (int i = 0; i < 32; i += 8) {
        float v = t[tx][ty + i];                       // = W[by+tx][bx+ty+i]
        long long o = (long long)(bx + ty + i) * R + by + tx;
        bf16 h = (bf16)v;
        Thi[o] = h;
        Tlo[o] = (bf16)(v - (float)h);
    }
}

// f16 [R][C] -> f16 [C][R], batched via blockIdx.z.
__global__ __launch_bounds__(256) void transpose_f16(const f16* __restrict__ in,
                                                     f16* __restrict__ out,
                                                     int R, int C, long long sIn, long long sOut)
{
    in  += (long long)blockIdx.z * sIn;
    out += (long long)blockIdx.z * sOut;
    __shared__ f16 t[32][33];
    const int bx = blockIdx.x * 32, by = blockIdx.y * 32;
    const int tx = threadIdx.x & 31, ty = threadIdx.x >> 5;
#pragma unroll
    for (int i = 0; i < 32; i += 8)
        t[ty + i][tx] = in[(long long)(by + ty + i) * C + bx + tx];
    __syncthreads();
#pragma unroll
    for (int i = 0; i < 32; i += 8)
        out[(long long)(bx + ty + i) * R + by + tx] = t[tx][ty + i];
}

// Row softmax fp32 -> f16. One 256-thread block per row of n=2048.
__global__ __launch_bounds__(256) void softmax_f16(const float* __restrict__ S,
                                                   f16* __restrict__ P, int n)
{
    const long long row = blockIdx.x;
    const float* p = S + row * (long long)n;
    f16* q = P + row * (long long)n;
    const int tid = threadIdx.x;
    const int wv = tid >> 6, lane = tid & 63;

    float v[8];
    float m = -3.4e38f;
#pragma unroll
    for (int i = 0; i < 8; i++) { v[i] = p[tid + (i << 8)]; m = fmaxf(m, v[i]); }
#pragma unroll
    for (int off = 32; off > 0; off >>= 1) m = fmaxf(m, __shfl_xor(m, off, 64));

    __shared__ float red[4];
    if (lane == 0) red[wv] = m;
    __syncthreads();
    m = fmaxf(fmaxf(red[0], red[1]), fmaxf(red[2], red[3]));

    float s = 0.f;
#pragma unroll
    for (int i = 0; i < 8; i++) { v[i] = __expf(v[i] - m); s += v[i]; }
#pragma unroll
    for (int off = 32; off > 0; off >>= 1) s += __shfl_xor(s, off, 64);
    __syncthreads();
    if (lane == 0) red[wv] = s;
    __syncthreads();
    s = red[0] + red[1] + red[2] + red[3];

    const float inv = 1.0f / s;
#pragma unroll
    for (int i = 0; i < 8; i++) q[tid + (i << 8)] = (f16)(v[i] * inv);
}

extern "C" void kernel_launch(void* const* d_in, const int* in_sizes, int n_in,
                              void* d_out, int out_size, void* d_ws, size_t ws_size,
                              hipStream_t stream) {
    const float* X  = (const float*)d_in[0];   // [8192,1024]
    const float* Wq = (const float*)d_in[1];   // [1024,1024]
    const float* Wk = (const float*)d_in[2];
    const float* Wv = (const float*)d_in[3];
    float* out = (float*)d_out;                // [8192,1024]

    const long long MD = 8192LL * 1024;
    const long long DD = 1024LL * 1024;

    char* w = (char*)d_ws;
    const long long MB = 1024LL * 1024;
    bf16* Xhi   = (bf16*)(w + 0 * MB);     // 16 MB
    bf16* Xlo   = (bf16*)(w + 16 * MB);    // 16 MB
    f16*  Xf    = (f16*) (w + 32 * MB);    // 16 MB
    bf16* Wq_h  = (bf16*)(w + 48 * MB);    // 2 MB (natural layout)
    bf16* Wq_l  = (bf16*)(w + 50 * MB);
    bf16* Wk_h  = (bf16*)(w + 52 * MB);
    bf16* Wk_l  = (bf16*)(w + 54 * MB);
    bf16* Wvt_h = (bf16*)(w + 56 * MB);    // 2 MB (transposed)
    bf16* Wvt_l = (bf16*)(w + 58 * MB);
    float* Mt   = (float*)(w + 60 * MB);   // 4 MB  (M^T = Wk Wq^T, fp32)
    bf16* Mt_h  = (bf16*)(w + 64 * MB);    // 2 MB
    bf16* Mt_l  = (bf16*)(w + 66 * MB);    // 2 MB
    f16*  T     = (f16*) (w + 68 * MB);    // 16 MB  [8192,1024]
    f16*  Vb    = (f16*) (w + 84 * MB);    // 16 MB
    f16*  Vt    = (f16*) (w + 100 * MB);   // 16 MB
    float* Sc   = (float*)(w + 116 * MB);  // 64 MB
    f16*  P     = (f16*) (w + 180 * MB);   // 32 MB -> ends 212 MB

    dim3 blk(256);

    // 1. split X into bf16 hi/lo + f16 copy
    split_x<<<dim3((unsigned)(MD / 4 / 256)), blk, 0, stream>>>(
        (const float4*)X, Xhi, Xlo, Xf, MD / 4);

    // 2. split Wq, Wk (natural layout, elementwise); transpose+split Wv
    split_x<<<dim3((unsigned)(DD / 4 / 256)), blk, 0, stream>>>(
        (const float4*)Wq, Wq_h, Wq_l, nullptr, DD / 4);
    split_x<<<dim3((unsigned)(DD / 4 / 256)), blk, 0, stream>>>(
        (const float4*)Wk, Wk_h, Wk_l, nullptr, DD / 4);
    wsplit_t<<<dim3(32, 32, 1), blk, 0, stream>>>(Wv, Wvt_h, Wvt_l, 1024, 1024);

    // 3. M^T = Wk Wq^T (split-bf16 3-MFMA), fp32 out [d'][d]
    gemm_bt<bf16, true, 0><<<dim3(8, 8, 1), blk, 0, stream>>>(
        Wk_h, Wk_l, Wq_h, Wq_l, Mt, nullptr,
        1024, 1024, 1024, 1024, 0, 0, 0);

    // 4. split M^T into bf16 hi/lo
    split_x<<<dim3((unsigned)(DD / 4 / 256)), blk, 0, stream>>>(
        (const float4*)Mt, Mt_h, Mt_l, nullptr, DD / 4);

    // 5. T = Xsplit . (M^T)split  -> f16 [8192,1024]
    gemm_bt<bf16, true, 1><<<dim3(8, 64, 1), blk, 0, stream>>>(
        Xhi, Xlo, Mt_h, Mt_l, nullptr, T,
        1024, 1024, 1024, 1024, 0, 0, 0);

    // 6. V projection (plain bf16), f16 out
    gemm_bt<bf16, false, 1><<<dim3(8, 64, 1), blk, 0, stream>>>(
        Xhi, nullptr, Wvt_h, nullptr, nullptr, Vb,
        1024, 1024, 1024, 1024, 0, 0, 0);

    // 7. V -> V^T per batch
    transpose_f16<<<dim3(1024 / 32, 2048 / 32, 4), blk, 0, stream>>>(
        Vb, Vt, 2048, 1024, 2048LL * 1024, 1024LL * 2048);

    // 8. scores = T . X^T per batch (plain f16), fp32 out
    gemm_bt<f16, false, 0><<<dim3(16, 16, 4), blk, 0, stream>>>(
        T, nullptr, Xf, nullptr, Sc, nullptr,
        1024, 1024, 1024, 2048,
        2048LL * 1024, 2048LL * 1024, 2048LL * 2048);

    // 9. softmax rows -> f16 P
    softmax_f16<<<dim3(4 * 2048), blk, 0, stream>>>(Sc, P, 2048);

    // 10. out = P V   (A = P [2048x2048], B = Vt [1024 x 2048])
    gemm_bt<f16, false, 0><<<dim3(8, 16, 4), blk, 0, stream>>>(
        P, nullptr, Vt, nullptr, out, nullptr,
        2048, 2048, 2048, 1024,
        2048LL * 2048, 1024LL * 2048, 2048LL * 1024);
}

// Round 5
// 352.778 us; speedup vs baseline: 4.3405x; 1.0801x over previous
//
#include <hip/hip_runtime.h>
#include <math.h>

// Round 5: BK=64 non-split GEMMs, int32 epilogues, fused V-transpose,
// direct-split M output. Pipeline:
//   Mt = Wk Wq^T (split-bf16 3-MFMA) -> bf16 hi/lo directly
//   T  = Xsplit . Mt_split (3-MFMA)  -> f16 [8192,1024]
//   Vt = (X . Wv)^T (plain bf16, LDS-transposed epilogue) -> f16 [4][1024][2048]
//   Sc = T . Xf^T (plain f16, BK=64) -> fp32
//   P  = softmax(Sc) -> f16
//   out= P . Vt^T (plain f16, BK=64) -> fp32

typedef __bf16 bf16;
typedef _Float16 f16;
typedef __bf16 bf16x8 __attribute__((ext_vector_type(8)));
typedef __bf16 bf16x4 __attribute__((ext_vector_type(4)));
typedef _Float16 f16x4 __attribute__((ext_vector_type(4)));
typedef _Float16 f16x8 __attribute__((ext_vector_type(8)));
typedef float  f32x4  __attribute__((ext_vector_type(4)));

template<typename E> struct vec8_of;
template<> struct vec8_of<bf16> { using type = bf16x8; };
template<> struct vec8_of<f16>  { using type = f16x8; };

__device__ inline f32x4 mfma16(bf16x8 a, bf16x8 b, f32x4 c) {
    return __builtin_amdgcn_mfma_f32_16x16x32_bf16(a, b, c, 0, 0, 0);
}
__device__ inline f32x4 mfma16(f16x8 a, f16x8 b, f32x4 c) {
    return __builtin_amdgcn_mfma_f32_16x16x32_f16(a, b, c, 0, 0, 0);
}

#define AS1 __attribute__((address_space(1)))
#define AS3 __attribute__((address_space(3)))

template<typename E>
__device__ inline void async_load16(const E* g, void* l) {
    __builtin_amdgcn_global_load_lds((const AS1 unsigned int*)g,
                                     (AS3 unsigned int*)l, 16, 0, 0);
}

// C[M,N] = sum_k A[m,k]*B[n,k]  (B passed [N,K]-layout, leading dim ldb).
// SPLIT: hi/lo pairs, hh + hl + lh (drop ll). BK: K-tile (32 split, 64 plain).
// OUT_MODE: 0 = fp32 C; 1 = f16 C; 2 = f16 C transposed per-batch (V path,
//           rows-per-batch hardcoded 2048, ldc = transposed row length);
//           3 = bf16 hi/lo pair.
template<typename E, bool SPLIT, int OUT_MODE, int BK>
__global__ __launch_bounds__(256) void gemm_bt(
    const E* __restrict__ Ahi, const E* __restrict__ Alo,
    const E* __restrict__ Bhi, const E* __restrict__ Blo,
    float* __restrict__ Cf, f16* __restrict__ Ch,
    bf16* __restrict__ Cbh, bf16* __restrict__ Cbl,
    int K, int lda, int ldb, int ldc,
    long long sA, long long sB, long long sC)
{
    using vec8 = typename vec8_of<E>::type;
    constexpr int NBUF = SPLIT ? 4 : 2;
    constexpr int TILE_BYTES = 128 * BK * (int)sizeof(E);   // 8192 or 16384
    constexpr int CPW = (TILE_BYTES / 1024) / 4;            // chunks per wave
    constexpr int SMB = (OUT_MODE == 2) ? (128 * 130 * 2 > NBUF * TILE_BYTES
                                           ? 128 * 130 * 2 : NBUF * TILE_BYTES)
                                        : NBUF * TILE_BYTES;

    __shared__ __align__(16) char smraw[SMB];
    auto smem = (E(*)[128][BK])smraw;         // smem[buf][row][k]
    auto tr   = (f16(*)[130])smraw;           // epilogue transpose (OUT_MODE 2)

    Ahi += (long long)blockIdx.z * sA;
    Bhi += (long long)blockIdx.z * sB;
    if (SPLIT) { Alo += (long long)blockIdx.z * sA; Blo += (long long)blockIdx.z * sB; }

    const int tid  = threadIdx.x;
    const int lane = tid & 63;
    const int wave = tid >> 6;
    const int quad = lane >> 4;
    const int l16  = lane & 15;
    const int wm   = (wave >> 1) * 64;
    const int wn   = (wave & 1) * 64;

    const long long rowA0 = (long long)blockIdx.y * 128;
    const long long colB0 = (long long)blockIdx.x * 128;

    // staging geometry: chunk = wave*CPW + u; byte off o = chunk*1024 + lane*16
    int ofs[CPW], rr[CPW], cc8[CPW];
#pragma unroll
    for (int u = 0; u < CPW; u++) {
        ofs[u] = (wave * CPW + u) * 1024 + lane * 16;
        rr[u]  = ofs[u] / (BK * 2);
        cc8[u] = (ofs[u] >> 4) & (BK / 8 - 1);
    }

    f32x4 acc[4][4];
#pragma unroll
    for (int i = 0; i < 4; i++)
#pragma unroll
        for (int j = 0; j < 4; j++) acc[i][j] = (f32x4){0.f, 0.f, 0.f, 0.f};

    for (int k0 = 0; k0 < K; k0 += BK) {
#pragma unroll
        for (int u = 0; u < CPW; u++) {
            async_load16(Ahi + (rowA0 + rr[u]) * lda + k0 + cc8[u] * 8, smraw + 0 * TILE_BYTES + ofs[u]);
            async_load16(Bhi + (colB0 + rr[u]) * ldb + k0 + cc8[u] * 8, smraw + 1 * TILE_BYTES + ofs[u]);
            if (SPLIT) {
                async_load16(Alo + (rowA0 + rr[u]) * lda + k0 + cc8[u] * 8, smraw + 2 * TILE_BYTES + ofs[u]);
                async_load16(Blo + (colB0 + rr[u]) * ldb + k0 + cc8[u] * 8, smraw + 3 * TILE_BYTES + ofs[u]);
            }
        }
        __syncthreads();

#pragma unroll
        for (int kh = 0; kh < BK / 32; kh++) {
            const int kc = kh * 32 + quad * 8;
            vec8 a_hi[4], b_hi[4], a_lo[4], b_lo[4];
#pragma unroll
            for (int i = 0; i < 4; i++) {
                a_hi[i] = *(const vec8*)&smem[0][wm + i * 16 + l16][kc];
                b_hi[i] = *(const vec8*)&smem[1][wn + i * 16 + l16][kc];
                if (SPLIT) {
                    a_lo[i] = *(const vec8*)&smem[2][wm + i * 16 + l16][kc];
                    b_lo[i] = *(const vec8*)&smem[3][wn + i * 16 + l16][kc];
                }
            }
#pragma unroll
            for (int i = 0; i < 4; i++)
#pragma unroll
                for (int j = 0; j < 4; j++) {
                    acc[i][j] = mfma16(a_hi[i], b_hi[j], acc[i][j]);
                    if (SPLIT) {
                        acc[i][j] = mfma16(a_hi[i], b_lo[j], acc[i][j]);
                        acc[i][j] = mfma16(a_lo[i], b_hi[j], acc[i][j]);
                    }
                }
        }
        __syncthreads();
    }

    if (OUT_MODE == 2) {
        // transpose 128x128 f16 tile through LDS (pad 130 -> conflict-light)
#pragma unroll
        for (int i = 0; i < 4; i++)
#pragma unroll
            for (int j = 0; j < 4; j++)
#pragma unroll
                for (int e = 0; e < 4; e++)
                    tr[wn + j * 16 + l16][wm + i * 16 + quad * 4 + e] = (f16)acc[i][j][e];
        __syncthreads();
        // out row (d) = colB0 + c; out col = row-in-batch + r. 2048 rows/batch.
        const int batch = (int)(rowA0 >> 11);
        const int rib   = (int)(rowA0 & 2047);
        const int c  = tid >> 1;
        const int r0 = (tid & 1) << 6;
        f16* vt = Ch + (long long)batch * 1024 * 2048 + (long long)(colB0 + c) * ldc + rib + r0;
#pragma unroll
        for (int u = 0; u < 64; u += 8)
            *(f16x8*)(vt + u) = *(const f16x8*)&tr[c][r0 + u];
        return;
    }

    // int32-offset epilogue: per-thread base + 16 row pointers + imm-offset stores
    const long long cOff = (long long)blockIdx.z * sC +
                           (rowA0 + wm + quad * 4) * (long long)ldc + colB0 + wn + l16;
#pragma unroll
    for (int i = 0; i < 4; i++)
#pragma unroll
        for (int e = 0; e < 4; e++) {
            const long long ro = cOff + (i * 16 + e) * ldc;
            if (OUT_MODE == 0) {
                float* rp = Cf + ro;
#pragma unroll
                for (int j = 0; j < 4; j++) rp[j * 16] = acc[i][j][e];
            } else if (OUT_MODE == 1) {
                f16* rp = Ch + ro;
#pragma unroll
                for (int j = 0; j < 4; j++) rp[j * 16] = (f16)acc[i][j][e];
            } else {  // OUT_MODE 3
                bf16* rh = Cbh + ro;
                bf16* rl = Cbl + ro;
#pragma unroll
                for (int j = 0; j < 4; j++) {
                    float v = acc[i][j][e];
                    bf16 h = (bf16)v;
                    rh[j * 16] = h;
                    rl[j * 16] = (bf16)(v - (float)h);
                }
            }
        }
}

// fp32 -> (hi, lo) bf16 + optional f16 copy, float4 per thread.
__global__ __launch_bounds__(256) void split_x(const float4* __restrict__ X,
                                               bf16* __restrict__ hi, bf16* __restrict__ lo,
                                               f16* __restrict__ xf,
                                               long long n4)
{
    long long i = (long long)blockIdx.x * 256 + threadIdx.x;
    if (i >= n4) return;
    float4 v = X[i];
    bf16 h0 = (bf16)v.x, h1 = (bf16)v.y, h2 = (bf16)v.z, h3 = (bf16)v.w;
    bf16x4 hv = {h0, h1, h2, h3};
    bf16x4 lv = {(bf16)(v.x - (float)h0), (bf16)(v.y - (float)h1),
                 (bf16)(v.z - (float)h2), (bf16)(v.w - (float)h3)};
    *(bf16x4*)(hi + 4 * i) = hv;
    *(bf16x4*)(lo + 4 * i) = lv;
    if (xf) {
        f16x4 fv = {(f16)v.x, (f16)v.y, (f16)v.z, (f16)v.w};
        *(f16x4*)(xf + 4 * i) = fv;
    }
}

// Two weight matrices split in one dispatch (blockIdx.z selects).
__global__ __launch_bounds__(256) void split_w2(const float4* __restrict__ W0,
                                                const float4* __restrict__ W1,
                                                bf16* __restrict__ h0, bf16* __restrict__ l0,
                                                bf16* __restrict__ h1, bf16* __restrict__ l1,
                                                long long n4)
{
    long long i = (long long)blockIdx.x * 256 + threadIdx.x;
    if (i >= n4) return;
    const float4* W = blockIdx.z ? W1 : W0;
    bf16* hh = blockIdx.z ? h1 : h0;
    bf16* ll = blockIdx.z ? l1 : l0;
    float4 v = W[i];
    bf16 a0 = (bf16)v.x, a1 = (bf16)v.y, a2 = (bf16)v.z, a3 = (bf16)v.w;
    bf16x4 hv = {a0, a1, a2, a3};
    bf16x4 lv = {(bf16)(v.x - (float)a0), (bf16)(v.y - (float)a1),
                 (bf16)(v.z - (float)a2), (bf16)(v.w - (float)a3)};
    *(bf16x4*)(hh + 4 * i) = hv;
    *(bf16x4*)(ll + 4 * i) = lv;
}

// W fp32 [R][C] -> transposed split bf16 [C][R] (hi, lo).
__global__ __launch_bounds__(256) void wsplit_t(const float* __restrict__ W,
                                                bf16* __restrict__ Thi, bf16* __restrict__ Tlo,
                                                int R, int C)
{
    __shared__ float t[32][33];
    const int bx = blockIdx.x * 32, by = blockIdx.y * 32;
    const int tx = threadIdx.x & 31, ty = threadIdx.x >> 5;
#pragma unroll
    for (int i = 0; i < 32; i += 8)
        t[ty + i][tx] = W[(long long)(by + ty + i) * C + bx + tx];
    __syncthreads();
#pragma unroll
    for (int i = 0; i < 32; i += 8) {
        float v = t[tx][ty + i];
        long long o = (long long)(bx + ty + i) * R + by + tx;
        bf16 h = (bf16)v;
        Thi[o] = h;
        Tlo[o] = (bf16)(v - (float)h);
    }
}

// Row softmax fp32 -> f16. One 256-thread block per row of n=2048.
__global__ __launch_bounds__(256) void softmax_f16(const float* __restrict__ S,
                                                   f16* __restrict__ P, int n)
{
    const long long row = blockIdx.x;
    const float* p = S + row * (long long)n;
    f16* q = P + row * (long long)n;
    const int tid = threadIdx.x;
    const int wv = tid >> 6, lane = tid & 63;

    float v[8];
    float m = -3.4e38f;
#pragma unroll
    for (int i = 0; i < 8; i++) { v[i] = p[tid + (i << 8)]; m = fmaxf(m, v[i]); }
#pragma unroll
    for (int off = 32; off > 0; off >>= 1) m = fmaxf(m, __shfl_xor(m, off, 64));

    __shared__ float red[4];
    if (lane == 0) red[wv] = m;
    __syncthreads();
    m = fmaxf(fmaxf(red[0], red[1]), fmaxf(red[2], red[3]));

    float s = 0.f;
#pragma unroll
    for (int i = 0; i < 8; i++) { v[i] = __expf(v[i] - m); s += v[i]; }
#pragma unroll
    for (int off = 32; off > 0; off >>= 1) s += __shfl_xor(s, off, 64);
    __syncthreads();
    if (lane == 0) red[wv] = s;
    __syncthreads();
    s = red[0] + red[1] + red[2] + red[3];

    const float inv = 1.0f / s;
#pragma unroll
    for (int i = 0; i < 8; i++) q[tid + (i << 8)] = (f16)(v[i] * inv);
}

extern "C" void kernel_launch(void* const* d_in, const int* in_sizes, int n_in,
                              void* d_out, int out_size, void* d_ws, size_t ws_size,
                              hipStream_t stream) {
    const float* X  = (const float*)d_in[0];   // [8192,1024]
    const float* Wq = (const float*)d_in[1];   // [1024,1024]
    const float* Wk = (const float*)d_in[2];
    const float* Wv = (const float*)d_in[3];
    float* out = (float*)d_out;                // [8192,1024]

    const long long MD = 8192LL * 1024;
    const long long DD = 1024LL * 1024;

    char* w = (char*)d_ws;
    const long long MB = 1024LL * 1024;
    bf16* Xhi   = (bf16*)(w + 0 * MB);     // 16 MB
    bf16* Xlo   = (bf16*)(w + 16 * MB);    // 16 MB
    f16*  Xf    = (f16*) (w + 32 * MB);    // 16 MB
    bf16* Wq_h  = (bf16*)(w + 48 * MB);    // 2 MB (natural layout)
    bf16* Wq_l  = (bf16*)(w + 50 * MB);
    bf16* Wk_h  = (bf16*)(w + 52 * MB);
    bf16* Wk_l  = (bf16*)(w + 54 * MB);
    bf16* Wvt_h = (bf16*)(w + 56 * MB);    // 2 MB (transposed)
    bf16* Wvt_l = (bf16*)(w + 58 * MB);
    bf16* Mt_h  = (bf16*)(w + 60 * MB);    // 2 MB
    bf16* Mt_l  = (bf16*)(w + 62 * MB);    // 2 MB
    f16*  T     = (f16*) (w + 64 * MB);    // 16 MB [8192,1024]
    f16*  Vt    = (f16*) (w + 80 * MB);    // 16 MB [4][1024][2048]
    float* Sc   = (float*)(w + 96 * MB);   // 64 MB
    f16*  P     = (f16*) (w + 160 * MB);   // 32 MB -> ends 192 MB

    dim3 blk(256);

    // 1. split X into bf16 hi/lo + f16 copy
    split_x<<<dim3((unsigned)(MD / 4 / 256)), blk, 0, stream>>>(
        (const float4*)X, Xhi, Xlo, Xf, MD / 4);

    // 2. split Wq+Wk (one dispatch); transpose+split Wv
    split_w2<<<dim3((unsigned)(DD / 4 / 256), 1, 2), blk, 0, stream>>>(
        (const float4*)Wq, (const float4*)Wk, Wq_h, Wq_l, Wk_h, Wk_l, DD / 4);
    wsplit_t<<<dim3(32, 32, 1), blk, 0, stream>>>(Wv, Wvt_h, Wvt_l, 1024, 1024);

    // 3. Mt = Wk Wq^T (split 3-MFMA), bf16 hi/lo out directly
    gemm_bt<bf16, true, 3, 32><<<dim3(8, 8, 1), blk, 0, stream>>>(
        Wk_h, Wk_l, Wq_h, Wq_l, nullptr, nullptr, Mt_h, Mt_l,
        1024, 1024, 1024, 1024, 0, 0, 0);

    // 4. T = Xsplit . Mt_split -> f16
    gemm_bt<bf16, true, 1, 32><<<dim3(8, 64, 1), blk, 0, stream>>>(
        Xhi, Xlo, Mt_h, Mt_l, nullptr, T, nullptr, nullptr,
        1024, 1024, 1024, 1024, 0, 0, 0);

    // 5. Vt = (X . Wv)^T per batch (plain bf16, fused transpose epilogue)
    gemm_bt<bf16, false, 2, 64><<<dim3(8, 64, 1), blk, 0, stream>>>(
        Xhi, nullptr, Wvt_h, nullptr, nullptr, Vt, nullptr, nullptr,
        1024, 1024, 1024, 2048, 0, 0, 0);

    // 6. Sc = T . Xf^T per batch (plain f16, BK=64), fp32 out
    gemm_bt<f16, false, 0, 64><<<dim3(16, 16, 4), blk, 0, stream>>>(
        T, nullptr, Xf, nullptr, Sc, nullptr, nullptr, nullptr,
        1024, 1024, 1024, 2048,
        2048LL * 1024, 2048LL * 1024, 2048LL * 2048);

    // 7. softmax rows -> f16 P
    softmax_f16<<<dim3(4 * 2048), blk, 0, stream>>>(Sc, P, 2048);

    // 8. out = P . Vt^T  (A = P [2048x2048] ld 2048, B = Vt [1024][2048] ld 2048)
    gemm_bt<f16, false, 0, 64><<<dim3(8, 16, 4), blk, 0, stream>>>(
        P, nullptr, Vt, nullptr, out, nullptr, nullptr, nullptr,
        2048, 2048, 2048, 1024,
        2048LL * 2048, 1024LL * 2048, 2048LL * 1024);
}

// Round 6
// 339.171 us; speedup vs baseline: 4.5146x; 1.0401x over previous
//
#include <hip/hip_runtime.h>
#include <math.h>

// Round 6: XOR-swizzled LDS for BK=64 tiles (row stride 128B = 32 banks made
// all fragment rows alias one 4-bank group -> 16-way conflict, MfmaUtil 21%).
// Chunk c of row r now lives at slot c^(r&7); staging permutes the *global*
// source per lane (LDS dest of global_load_lds stays lane-contiguous).
// Pipeline unchanged from R5:
//   Mt = Wk Wq^T (split-bf16) -> bf16 hi/lo
//   T  = Xsplit . Mt_split    -> f16 [8192,1024]
//   Vt = (X . Wv)^T           -> f16 [4][1024][2048]  (fused transpose)
//   Sc = T . Xf^T             -> fp32
//   P  = softmax(Sc)          -> f16
//   out= P . Vt^T             -> fp32

typedef __bf16 bf16;
typedef _Float16 f16;
typedef __bf16 bf16x8 __attribute__((ext_vector_type(8)));
typedef __bf16 bf16x4 __attribute__((ext_vector_type(4)));
typedef _Float16 f16x4 __attribute__((ext_vector_type(4)));
typedef _Float16 f16x8 __attribute__((ext_vector_type(8)));
typedef float  f32x4  __attribute__((ext_vector_type(4)));

template<typename E> struct vec8_of;
template<> struct vec8_of<bf16> { using type = bf16x8; };
template<> struct vec8_of<f16>  { using type = f16x8; };

__device__ inline f32x4 mfma16(bf16x8 a, bf16x8 b, f32x4 c) {
    return __builtin_amdgcn_mfma_f32_16x16x32_bf16(a, b, c, 0, 0, 0);
}
__device__ inline f32x4 mfma16(f16x8 a, f16x8 b, f32x4 c) {
    return __builtin_amdgcn_mfma_f32_16x16x32_f16(a, b, c, 0, 0, 0);
}

#define AS1 __attribute__((address_space(1)))
#define AS3 __attribute__((address_space(3)))

template<typename E>
__device__ inline void async_load16(const E* g, void* l) {
    __builtin_amdgcn_global_load_lds((const AS1 unsigned int*)g,
                                     (AS3 unsigned int*)l, 16, 0, 0);
}

// C[M,N] = sum_k A[m,k]*B[n,k]  (B passed [N,K]-layout, leading dim ldb).
// SPLIT: hi/lo pairs, hh + hl + lh. BK: K-tile (32 split, 64 plain).
// OUT_MODE: 0 = fp32 C; 1 = f16 C; 2 = f16 C transposed per-batch (V path);
//           3 = bf16 hi/lo pair.
template<typename E, bool SPLIT, int OUT_MODE, int BK>
__global__ __launch_bounds__(256) void gemm_bt(
    const E* __restrict__ Ahi, const E* __restrict__ Alo,
    const E* __restrict__ Bhi, const E* __restrict__ Blo,
    float* __restrict__ Cf, f16* __restrict__ Ch,
    bf16* __restrict__ Cbh, bf16* __restrict__ Cbl,
    int K, int lda, int ldb, int ldc,
    long long sA, long long sB, long long sC)
{
    using vec8 = typename vec8_of<E>::type;
    constexpr int NBUF = SPLIT ? 4 : 2;
    constexpr int TILE_BYTES = 128 * BK * (int)sizeof(E);   // 8192 or 16384
    constexpr int CPW = (TILE_BYTES / 1024) / 4;            // 1KB chunks per wave
    constexpr int SPR = (BK * (int)sizeof(E)) / 16;         // 16B slots per row
    constexpr int SWZ = (SPR == 8) ? 7 : 0;                 // swizzle mask (BK=64 only)
    constexpr int SMB = (OUT_MODE == 2) ? (128 * 130 * 2 > NBUF * TILE_BYTES
                                           ? 128 * 130 * 2 : NBUF * TILE_BYTES)
                                        : NBUF * TILE_BYTES;

    __shared__ __align__(16) char smraw[SMB];
    auto tr = (f16(*)[130])smraw;             // epilogue transpose (OUT_MODE 2)

    Ahi += (long long)blockIdx.z * sA;
    Bhi += (long long)blockIdx.z * sB;
    if (SPLIT) { Alo += (long long)blockIdx.z * sA; Blo += (long long)blockIdx.z * sB; }

    const int tid  = threadIdx.x;
    const int lane = tid & 63;
    const int wave = tid >> 6;
    const int quad = lane >> 4;
    const int l16  = lane & 15;
    const int wm   = (wave >> 1) * 64;
    const int wn   = (wave & 1) * 64;

    const long long rowA0 = (long long)blockIdx.y * 128;
    const long long colB0 = (long long)blockIdx.x * 128;

    // staging geometry: chunk = wave*CPW + u; byte off o = chunk*1024 + lane*16.
    // LDS slot s = o/16 -> row = s/SPR, phys chunk = s%SPR; the *global* source
    // chunk is phys ^ (row & SWZ) so reads can de-alias banks.
    int ofs[CPW], rr[CPW], cc8[CPW];
#pragma unroll
    for (int u = 0; u < CPW; u++) {
        ofs[u] = (wave * CPW + u) * 1024 + lane * 16;
        const int s = ofs[u] >> 4;
        rr[u]  = s / SPR;
        cc8[u] = (s & (SPR - 1)) ^ (rr[u] & SWZ);
    }

    f32x4 acc[4][4];
#pragma unroll
    for (int i = 0; i < 4; i++)
#pragma unroll
        for (int j = 0; j < 4; j++) acc[i][j] = (f32x4){0.f, 0.f, 0.f, 0.f};

    for (int k0 = 0; k0 < K; k0 += BK) {
#pragma unroll
        for (int u = 0; u < CPW; u++) {
            async_load16(Ahi + (rowA0 + rr[u]) * lda + k0 + cc8[u] * 8, smraw + 0 * TILE_BYTES + ofs[u]);
            async_load16(Bhi + (colB0 + rr[u]) * ldb + k0 + cc8[u] * 8, smraw + 1 * TILE_BYTES + ofs[u]);
            if (SPLIT) {
                async_load16(Alo + (rowA0 + rr[u]) * lda + k0 + cc8[u] * 8, smraw + 2 * TILE_BYTES + ofs[u]);
                async_load16(Blo + (colB0 + rr[u]) * ldb + k0 + cc8[u] * 8, smraw + 3 * TILE_BYTES + ofs[u]);
            }
        }
        __syncthreads();

#pragma unroll
        for (int kh = 0; kh < BK / 32; kh++) {
            const int kc8 = kh * 4 + quad;    // 16B chunk index within row
            vec8 a_hi[4], b_hi[4], a_lo[4], b_lo[4];
#pragma unroll
            for (int i = 0; i < 4; i++) {
                const int ra = wm + i * 16 + l16;
                const int rb = wn + i * 16 + l16;
                const int oa = ra * (SPR * 16) + ((kc8 ^ (ra & SWZ)) << 4);
                const int ob = rb * (SPR * 16) + ((kc8 ^ (rb & SWZ)) << 4);
                a_hi[i] = *(const vec8*)(smraw + 0 * TILE_BYTES + oa);
                b_hi[i] = *(const vec8*)(smraw + 1 * TILE_BYTES + ob);
                if (SPLIT) {
                    a_lo[i] = *(const vec8*)(smraw + 2 * TILE_BYTES + oa);
                    b_lo[i] = *(const vec8*)(smraw + 3 * TILE_BYTES + ob);
                }
            }
#pragma unroll
            for (int i = 0; i < 4; i++)
#pragma unroll
                for (int j = 0; j < 4; j++) {
                    acc[i][j] = mfma16(a_hi[i], b_hi[j], acc[i][j]);
                    if (SPLIT) {
                        acc[i][j] = mfma16(a_hi[i], b_lo[j], acc[i][j]);
                        acc[i][j] = mfma16(a_lo[i], b_hi[j], acc[i][j]);
                    }
                }
        }
        __syncthreads();
    }

    if (OUT_MODE == 2) {
        // transpose 128x128 f16 tile through LDS (pad 130 -> conflict-light)
#pragma unroll
        for (int i = 0; i < 4; i++)
#pragma unroll
            for (int j = 0; j < 4; j++)
#pragma unroll
                for (int e = 0; e < 4; e++)
                    tr[wn + j * 16 + l16][wm + i * 16 + quad * 4 + e] = (f16)acc[i][j][e];
        __syncthreads();
        const int batch = (int)(rowA0 >> 11);
        const int rib   = (int)(rowA0 & 2047);
        const int c  = tid >> 1;
        const int r0 = (tid & 1) << 6;
        f16* vt = Ch + (long long)batch * 1024 * 2048 + (long long)(colB0 + c) * ldc + rib + r0;
#pragma unroll
        for (int u = 0; u < 64; u += 8)
            *(f16x8*)(vt + u) = *(const f16x8*)&tr[c][r0 + u];
        return;
    }

    // int32-offset epilogue
    const long long cOff = (long long)blockIdx.z * sC +
                           (rowA0 + wm + quad * 4) * (long long)ldc + colB0 + wn + l16;
#pragma unroll
    for (int i = 0; i < 4; i++)
#pragma unroll
        for (int e = 0; e < 4; e++) {
            const long long ro = cOff + (i * 16 + e) * ldc;
            if (OUT_MODE == 0) {
                float* rp = Cf + ro;
#pragma unroll
                for (int j = 0; j < 4; j++) rp[j * 16] = acc[i][j][e];
            } else if (OUT_MODE == 1) {
                f16* rp = Ch + ro;
#pragma unroll
                for (int j = 0; j < 4; j++) rp[j * 16] = (f16)acc[i][j][e];
            } else {  // OUT_MODE 3
                bf16* rh = Cbh + ro;
                bf16* rl = Cbl + ro;
#pragma unroll
                for (int j = 0; j < 4; j++) {
                    float v = acc[i][j][e];
                    bf16 h = (bf16)v;
                    rh[j * 16] = h;
                    rl[j * 16] = (bf16)(v - (float)h);
                }
            }
        }
}

// fp32 -> (hi, lo) bf16 + optional f16 copy, float4 per thread.
__global__ __launch_bounds__(256) void split_x(const float4* __restrict__ X,
                                               bf16* __restrict__ hi, bf16* __restrict__ lo,
                                               f16* __restrict__ xf,
                                               long long n4)
{
    long long i = (long long)blockIdx.x * 256 + threadIdx.x;
    if (i >= n4) return;
    float4 v = X[i];
    bf16 h0 = (bf16)v.x, h1 = (bf16)v.y, h2 = (bf16)v.z, h3 = (bf16)v.w;
    bf16x4 hv = {h0, h1, h2, h3};
    bf16x4 lv = {(bf16)(v.x - (float)h0), (bf16)(v.y - (float)h1),
                 (bf16)(v.z - (float)h2), (bf16)(v.w - (float)h3)};
    *(bf16x4*)(hi + 4 * i) = hv;
    *(bf16x4*)(lo + 4 * i) = lv;
    if (xf) {
        f16x4 fv = {(f16)v.x, (f16)v.y, (f16)v.z, (f16)v.w};
        *(f16x4*)(xf + 4 * i) = fv;
    }
}

// Two weight matrices split in one dispatch (blockIdx.z selects).
__global__ __launch_bounds__(256) void split_w2(const float4* __restrict__ W0,
                                                const float4* __restrict__ W1,
                                                bf16* __restrict__ h0, bf16* __restrict__ l0,
                                                bf16* __restrict__ h1, bf16* __restrict__ l1,
                                                long long n4)
{
    long long i = (long long)blockIdx.x * 256 + threadIdx.x;
    if (i >= n4) return;
    const float4* W = blockIdx.z ? W1 : W0;
    bf16* hh = blockIdx.z ? h1 : h0;
    bf16* ll = blockIdx.z ? l1 : l0;
    float4 v = W[i];
    bf16 a0 = (bf16)v.x, a1 = (bf16)v.y, a2 = (bf16)v.z, a3 = (bf16)v.w;
    bf16x4 hv = {a0, a1, a2, a3};
    bf16x4 lv = {(bf16)(v.x - (float)a0), (bf16)(v.y - (float)a1),
                 (bf16)(v.z - (float)a2), (bf16)(v.w - (float)a3)};
    *(bf16x4*)(hh + 4 * i) = hv;
    *(bf16x4*)(ll + 4 * i) = lv;
}

// W fp32 [R][C] -> transposed split bf16 [C][R] (hi, lo).
__global__ __launch_bounds__(256) void wsplit_t(const float* __restrict__ W,
                                                bf16* __restrict__ Thi, bf16* __restrict__ Tlo,
                                                int R, int C)
{
    __shared__ float t[32][33];
    const int bx = blockIdx.x * 32, by = blockIdx.y * 32;
    const int tx = threadIdx.x & 31, ty = threadIdx.x >> 5;
#pragma unroll
    for (int i = 0; i < 32; i += 8)
        t[ty + i][tx] = W[(long long)(by + ty + i) * C + bx + tx];
    __syncthreads();
#pragma unroll
    for (int i = 0; i < 32; i += 8) {
        float v = t[tx][ty + i];
        long long o = (long long)(bx + ty + i) * R + by + tx;
        bf16 h = (bf16)v;
        Thi[o] = h;
        Tlo[o] = (bf16)(v - (float)h);
    }
}

// Row softmax fp32 -> f16. One 256-thread block per row of n=2048.
__global__ __launch_bounds__(256) void softmax_f16(const float* __restrict__ S,
                                                   f16* __restrict__ P, int n)
{
    const long long row = blockIdx.x;
    const float* p = S + row * (long long)n;
    f16* q = P + row * (long long)n;
    const int tid = threadIdx.x;
    const int wv = tid >> 6, lane = tid & 63;

    float v[8];
    float m = -3.4e38f;
#pragma unroll
    for (int i = 0; i < 8; i++) { v[i] = p[tid + (i << 8)]; m = fmaxf(m, v[i]); }
#pragma unroll
    for (int off = 32; off > 0; off >>= 1) m = fmaxf(m, __shfl_xor(m, off, 64));

    __shared__ float red[4];
    if (lane == 0) red[wv] = m;
    __syncthreads();
    m = fmaxf(fmaxf(red[0], red[1]), fmaxf(red[2], red[3]));

    float s = 0.f;
#pragma unroll
    for (int i = 0; i < 8; i++) { v[i] = __expf(v[i] - m); s += v[i]; }
#pragma unroll
    for (int off = 32; off > 0; off >>= 1) s += __shfl_xor(s, off, 64);
    __syncthreads();
    if (lane == 0) red[wv] = s;
    __syncthreads();
    s = red[0] + red[1] + red[2] + red[3];

    const float inv = 1.0f / s;
#pragma unroll
    for (int i = 0; i < 8; i++) q[tid + (i << 8)] = (f16)(v[i] * inv);
}

extern "C" void kernel_launch(void* const* d_in, const int* in_sizes, int n_in,
                              void* d_out, int out_size, void* d_ws, size_t ws_size,
                              hipStream_t stream) {
    const float* X  = (const float*)d_in[0];   // [8192,1024]
    const float* Wq = (const float*)d_in[1];   // [1024,1024]
    const float* Wk = (const float*)d_in[2];
    const float* Wv = (const float*)d_in[3];
    float* out = (float*)d_out;                // [8192,1024]

    const long long MD = 8192LL * 1024;
    const long long DD = 1024LL * 1024;

    char* w = (char*)d_ws;
    const long long MB = 1024LL * 1024;
    bf16* Xhi   = (bf16*)(w + 0 * MB);     // 16 MB
    bf16* Xlo   = (bf16*)(w + 16 * MB);    // 16 MB
    f16*  Xf    = (f16*) (w + 32 * MB);    // 16 MB
    bf16* Wq_h  = (bf16*)(w + 48 * MB);    // 2 MB (natural layout)
    bf16* Wq_l  = (bf16*)(w + 50 * MB);
    bf16* Wk_h  = (bf16*)(w + 52 * MB);
    bf16* Wk_l  = (bf16*)(w + 54 * MB);
    bf16* Wvt_h = (bf16*)(w + 56 * MB);    // 2 MB (transposed)
    bf16* Wvt_l = (bf16*)(w + 58 * MB);
    bf16* Mt_h  = (bf16*)(w + 60 * MB);    // 2 MB
    bf16* Mt_l  = (bf16*)(w + 62 * MB);    // 2 MB
    f16*  T     = (f16*) (w + 64 * MB);    // 16 MB [8192,1024]
    f16*  Vt    = (f16*) (w + 80 * MB);    // 16 MB [4][1024][2048]
    float* Sc   = (float*)(w + 96 * MB);   // 64 MB
    f16*  P     = (f16*) (w + 160 * MB);   // 32 MB -> ends 192 MB

    dim3 blk(256);

    // 1. split X into bf16 hi/lo + f16 copy
    split_x<<<dim3((unsigned)(MD / 4 / 256)), blk, 0, stream>>>(
        (const float4*)X, Xhi, Xlo, Xf, MD / 4);

    // 2. split Wq+Wk (one dispatch); transpose+split Wv
    split_w2<<<dim3((unsigned)(DD / 4 / 256), 1, 2), blk, 0, stream>>>(
        (const float4*)Wq, (const float4*)Wk, Wq_h, Wq_l, Wk_h, Wk_l, DD / 4);
    wsplit_t<<<dim3(32, 32, 1), blk, 0, stream>>>(Wv, Wvt_h, Wvt_l, 1024, 1024);

    // 3. Mt = Wk Wq^T (split 3-MFMA), bf16 hi/lo out directly
    gemm_bt<bf16, true, 3, 32><<<dim3(8, 8, 1), blk, 0, stream>>>(
        Wk_h, Wk_l, Wq_h, Wq_l, nullptr, nullptr, Mt_h, Mt_l,
        1024, 1024, 1024, 1024, 0, 0, 0);

    // 4. T = Xsplit . Mt_split -> f16
    gemm_bt<bf16, true, 1, 32><<<dim3(8, 64, 1), blk, 0, stream>>>(
        Xhi, Xlo, Mt_h, Mt_l, nullptr, T, nullptr, nullptr,
        1024, 1024, 1024, 1024, 0, 0, 0);

    // 5. Vt = (X . Wv)^T per batch (plain bf16, fused transpose epilogue)
    gemm_bt<bf16, false, 2, 64><<<dim3(8, 64, 1), blk, 0, stream>>>(
        Xhi, nullptr, Wvt_h, nullptr, nullptr, Vt, nullptr, nullptr,
        1024, 1024, 1024, 2048, 0, 0, 0);

    // 6. Sc = T . Xf^T per batch (plain f16, BK=64), fp32 out
    gemm_bt<f16, false, 0, 64><<<dim3(16, 16, 4), blk, 0, stream>>>(
        T, nullptr, Xf, nullptr, Sc, nullptr, nullptr, nullptr,
        1024, 1024, 1024, 2048,
        2048LL * 1024, 2048LL * 1024, 2048LL * 2048);

    // 7. softmax rows -> f16 P
    softmax_f16<<<dim3(4 * 2048), blk, 0, stream>>>(Sc, P, 2048);

    // 8. out = P . Vt^T  (A = P [2048x2048] ld 2048, B = Vt [1024][2048] ld 2048)
    gemm_bt<f16, false, 0, 64><<<dim3(8, 16, 4), blk, 0, stream>>>(
        P, nullptr, Vt, nullptr, out, nullptr, nullptr, nullptr,
        2048, 2048, 2048, 1024,
        2048LL * 2048, 1024LL * 2048, 2048LL * 1024);
}